// Round 2
// baseline (300.956 us; speedup 1.0000x reference)
//
#include <hip/hip_runtime.h>

// DenseGrid multi-LOD bilinear interpolation.
// LODS = 16,32,64,128,256,512,1024,2048 ; FEAT_DIM=4 ; N=2,000,000
// Output: [N, 32] float32.
// Layout: 8 threads per point, one per LOD -> coalesced 16B output stores.

typedef float fx4 __attribute__((ext_vector_type(4)));
typedef float fx2 __attribute__((ext_vector_type(2)));

__global__ __launch_bounds__(256) void densegrid_kernel(
    const float* __restrict__ xin,
    const float* __restrict__ g0, const float* __restrict__ g1,
    const float* __restrict__ g2, const float* __restrict__ g3,
    const float* __restrict__ g4, const float* __restrict__ g5,
    const float* __restrict__ g6, const float* __restrict__ g7,
    float* __restrict__ out, int npts)
{
    int tid = blockIdx.x * blockDim.x + threadIdx.x;
    int n   = tid >> 3;
    if (n >= npts) return;
    int lod = tid & 7;

    // Ternary-tree select (v_cndmask pairs), NOT an indexed array (scratch!).
    const float* g =
        (lod < 4) ? ((lod < 2) ? ((lod == 0) ? g0 : g1)
                               : ((lod == 2) ? g2 : g3))
                  : ((lod < 6) ? ((lod == 4) ? g4 : g5)
                               : ((lod == 6) ? g6 : g7));
    int res = 16 << lod;

    // 8 lanes per point read the same 8B -> broadcast from cache.
    fx2 p = *(const fx2*)(xin + (size_t)n * 2);

    float rm1 = (float)(res - 1);
    float fx = p.x * rm1;
    float fy = p.y * rm1;

    // clip ONLY for the floor/index (reference semantics); weights use fx,fy.
    float cmax = rm1 - 1e-5f;
    float xc = fminf(fmaxf(fx, 0.0f), cmax);
    float yc = fminf(fmaxf(fy, 0.0f), cmax);
    int x1 = (int)floorf(xc);
    int y1 = (int)floorf(yc);
    int x2 = min(x1 + 1, res - 1);
    int y2 = min(y1 + 1, res - 1);

    float x1f = (float)x1, y1f = (float)y1;
    float x2f = (float)x2, y2f = (float)y2;
    float w1 = (x2f - fx) * (y2f - fy);
    float w2 = (fx - x1f) * (y2f - fy);
    float w3 = (x2f - fx) * (fy - y1f);
    float w4 = (fx - x1f) * (fy - y1f);

    const fx4* gc = (const fx4*)g;
    fx4 v1 = gc[x1 + y1 * res];
    fx4 v2 = gc[x2 + y1 * res];
    fx4 v3 = gc[x1 + y2 * res];
    fx4 v4 = gc[x2 + y2 * res];

    fx4 o = w1 * v1 + w2 * v2 + w3 * v3 + w4 * v4;

    // Nontemporal: don't let the 256MB output stream evict grids from L3.
    __builtin_nontemporal_store(o, (fx4*)out + (size_t)n * 8 + lod);
}

extern "C" void kernel_launch(void* const* d_in, const int* in_sizes, int n_in,
                              void* d_out, int out_size, void* d_ws, size_t ws_size,
                              hipStream_t stream) {
    const float* x  = (const float*)d_in[0];
    const float* g0 = (const float*)d_in[1];
    const float* g1 = (const float*)d_in[2];
    const float* g2 = (const float*)d_in[3];
    const float* g3 = (const float*)d_in[4];
    const float* g4 = (const float*)d_in[5];
    const float* g5 = (const float*)d_in[6];
    const float* g6 = (const float*)d_in[7];
    const float* g7 = (const float*)d_in[8];
    float* out = (float*)d_out;

    int npts = in_sizes[0] / 2;           // x is [N,2]
    int total = npts * 8;                 // 8 lod-threads per point
    int block = 256;
    int grid  = (total + block - 1) / block;

    densegrid_kernel<<<grid, block, 0, stream>>>(
        x, g0, g1, g2, g3, g4, g5, g6, g7, out, npts);
}